// Round 1
// baseline (1116.410 us; speedup 1.0000x reference)
//
#include <hip/hip_runtime.h>
#include <cmath>

// Problem constants
#define NB 8
#define NPTS 4096
#define NPT 1024
#define NSAMP 32
#define MTOT (NB*NPT*NSAMP)   // 262144 rows for the MLP
#define NBLK 4096             // MTOT/64 GEMM blocks

// ---------------------------------------------------------------------------
// Stage 1: farthest point sampling. One block per batch. Bitwise-exact f32
// replication of the reference (no FMA contraction, (dx2+dy2)+dz2 order,
// argmax with first-index tie-break). Writes new_xyz directly into d_out.
// ---------------------------------------------------------------------------
__global__ __launch_bounds__(256) void fps_kernel(const float* __restrict__ xyz,
                                                  float* __restrict__ new_xyz) {
  const int b = blockIdx.x;
  const int t = threadIdx.x;
  __shared__ float sx[NPTS], sy[NPTS], sz[NPTS];
  __shared__ unsigned long long red[2][4];
  const float* X = xyz + (size_t)b * NPTS * 3;
  float px[16], py[16], pz[16], dist[16];
#pragma unroll
  for (int i = 0; i < 16; ++i) {
    int p = i * 256 + t;
    float x = X[p * 3 + 0], y = X[p * 3 + 1], z = X[p * 3 + 2];
    px[i] = x; py[i] = y; pz[i] = z;
    sx[p] = x; sy[p] = y; sz[p] = z;
    dist[i] = 1e10f;
  }
  __syncthreads();
  int far = 0;
  float* outp = new_xyz + (size_t)b * NPT * 3;
  for (int s = 0; s < NPT; ++s) {
    float cx = sx[far], cy = sy[far], cz = sz[far];
    if (t == 0) { outp[s * 3 + 0] = cx; outp[s * 3 + 1] = cy; outp[s * 3 + 2] = cz; }
    float bestv = -1.0f; int besti = t;
#pragma unroll
    for (int i = 0; i < 16; ++i) {
      float dx = __fsub_rn(px[i], cx);
      float dy = __fsub_rn(py[i], cy);
      float dz = __fsub_rn(pz[i], cz);
      float d = __fadd_rn(__fadd_rn(__fmul_rn(dx, dx), __fmul_rn(dy, dy)), __fmul_rn(dz, dz));
      float nd = fminf(dist[i], d);
      dist[i] = nd;
      if (nd > bestv) { bestv = nd; besti = i * 256 + t; }  // ascending p -> lowest idx on tie
    }
    // pack: higher value wins; equal value -> smaller index wins
    unsigned long long key = ((unsigned long long)__float_as_uint(bestv) << 32)
                           | (unsigned int)(~besti);
#pragma unroll
    for (int off = 32; off >= 1; off >>= 1) {
      unsigned long long other = __shfl_xor(key, off, 64);
      if (other > key) key = other;
    }
    if ((t & 63) == 0) red[s & 1][t >> 6] = key;
    __syncthreads();
    unsigned long long k0 = red[s & 1][0], k1 = red[s & 1][1];
    unsigned long long k2 = red[s & 1][2], k3 = red[s & 1][3];
    if (k1 > k0) k0 = k1;
    if (k3 > k2) k2 = k3;
    if (k2 > k0) k0 = k2;
    far = (int)(~(unsigned int)k0);
  }
}

// ---------------------------------------------------------------------------
// Stage 2: ball query. One wave per (b,s). First 32 indices in ascending order
// with dist <= r^2; pad with first match.
// ---------------------------------------------------------------------------
__global__ __launch_bounds__(256) void ballq_kernel(const float* __restrict__ xyz,
                                                    const float* __restrict__ new_xyz,
                                                    int* __restrict__ gidx) {
  int w = (blockIdx.x * 256 + threadIdx.x) >> 6;   // 8192 waves
  int lane = threadIdx.x & 63;
  int b = w >> 10;
  const float* X = xyz + (size_t)b * NPTS * 3;
  float cx = new_xyz[w * 3 + 0], cy = new_xyz[w * 3 + 1], cz = new_xyz[w * 3 + 2];
  int* out = gidx + (size_t)w * NSAMP;
  int cnt = 0, first = -1;
  for (int c = 0; c < NPTS / 64; ++c) {
    int p = c * 64 + lane;
    float dx = __fsub_rn(X[p * 3 + 0], cx);
    float dy = __fsub_rn(X[p * 3 + 1], cy);
    float dz = __fsub_rn(X[p * 3 + 2], cz);
    float d = __fadd_rn(__fadd_rn(__fmul_rn(dx, dx), __fmul_rn(dy, dy)), __fmul_rn(dz, dz));
    bool inr = !(d > 0.04f);   // f32(0.2**2) == 0.04f
    unsigned long long mask = __ballot(inr);
    if (mask) {
      if (first < 0) first = c * 64 + (int)__builtin_ctzll(mask);
      if (inr) {
        int pos = cnt + (int)__builtin_popcountll(mask & ((1ull << lane) - 1ull));
        if (pos < NSAMP) out[pos] = p;
      }
      cnt += (int)__builtin_popcountll(mask);
      if (cnt >= NSAMP) break;
    }
  }
  if (lane >= cnt && lane < NSAMP) out[lane] = first;
}

// ---------------------------------------------------------------------------
// Stage 3: gather + concat -> X0 (MTOT x 68, col67 zero pad)
// ---------------------------------------------------------------------------
__global__ __launch_bounds__(256) void gather_kernel(const float* __restrict__ xyz,
                                                     const float* __restrict__ points,
                                                     const float* __restrict__ new_xyz,
                                                     const int* __restrict__ gidx,
                                                     float* __restrict__ X0) {
  int gid = blockIdx.x * 256 + threadIdx.x;       // < MTOT*68 exactly
  int m = gid / 68;
  int c = gid - m * 68;
  int idx = gidx[m];
  int b = m >> 15;                                 // 32768 rows per batch
  float v;
  if (c < 3) {
    v = __fsub_rn(xyz[((size_t)b * NPTS + idx) * 3 + c],
                  new_xyz[(size_t)(m >> 5) * 3 + c]);
  } else if (c < 67) {
    v = points[((size_t)b * NPTS + idx) * 64 + (c - 3)];
  } else {
    v = 0.0f;
  }
  X0[gid] = v;
}

// ---------------------------------------------------------------------------
// Stage 4: MLP layer GEMM. 64xO tile per block, 256 threads.
// Thread (to=t&15, tm=t>>4) computes rows 4*tm..+3, cols OJ*to..+OJ-1.
// Optionally applies previous layer's BN+ReLU (a,d) while staging input.
// Writes per-block per-channel sum / sumsq partials (deterministic stats).
// DO_MM: instead of writing Y, max/min-pool pre-activations over k (32 rows).
// ---------------------------------------------------------------------------
template<int KDIM, int XSTRIDE, int O, bool NORM_IN, bool WRITE_Y, bool DO_MM>
__global__ __launch_bounds__(256) void mlp_gemm(const float* __restrict__ Xg,
                                                const float* __restrict__ Wg,
                                                const float* __restrict__ bias,
                                                const float* __restrict__ ad,
                                                float* __restrict__ Yg,
                                                float* __restrict__ partials,
                                                float* __restrict__ mm) {
  constexpr int KP = (KDIM + 3) & ~3;   // 68 or 64
  constexpr int KP4 = KP / 4;
  constexpr int OJ = O / 16;            // 4 or 8
  __shared__ __align__(16) float sX[64 * 68];
  __shared__ __align__(16) float sWt[KP * O];
  const int t = threadIdx.x;
  const int m0 = blockIdx.x * 64;

  // stage W transposed: sWt[k*O+o] = W[o*KDIM+k]; consecutive t -> consecutive o
  for (int i = t; i < O * KDIM; i += 256) {
    int k = i / O;            // O is power of 2
    int o = i - k * O;
    sWt[k * O + o] = Wg[o * KDIM + k];
  }
  if (KP > KDIM) {
    if (t < O) {
      for (int k = KDIM; k < KP; ++k) sWt[k * O + t] = 0.0f;
    }
  }
  // stage X tile (apply BN+ReLU of previous layer if NORM_IN)
  {
    int r = t >> 2, q = t & 3;
    const float* src = Xg + (size_t)(m0 + r) * XSTRIDE;
    for (int c4 = q; c4 < KP4; c4 += 4) {
      float4 v = *(const float4*)(src + 4 * c4);
      if constexpr (NORM_IN) {
        float4 a = *(const float4*)(ad + 4 * c4);
        float4 d = *(const float4*)(ad + 128 + 4 * c4);
        v.x = fmaxf(fmaf(a.x, v.x, d.x), 0.0f);
        v.y = fmaxf(fmaf(a.y, v.y, d.y), 0.0f);
        v.z = fmaxf(fmaf(a.z, v.z, d.z), 0.0f);
        v.w = fmaxf(fmaf(a.w, v.w, d.w), 0.0f);
      }
      *(float4*)&sX[r * 68 + 4 * c4] = v;
    }
  }
  __syncthreads();

  const int to = t & 15, tm = t >> 4;
  float acc[4][OJ];
#pragma unroll
  for (int i = 0; i < 4; ++i)
#pragma unroll
    for (int j = 0; j < OJ; ++j) acc[i][j] = 0.0f;

#pragma unroll
  for (int k4 = 0; k4 < KP4; ++k4) {
    float xs[4][4];
#pragma unroll
    for (int i = 0; i < 4; ++i) {
      float4 v = *(const float4*)&sX[(4 * tm + i) * 68 + 4 * k4];
      xs[i][0] = v.x; xs[i][1] = v.y; xs[i][2] = v.z; xs[i][3] = v.w;
    }
#pragma unroll
    for (int kk = 0; kk < 4; ++kk) {
      float wv[OJ];
#pragma unroll
      for (int j4 = 0; j4 < OJ / 4; ++j4) {
        float4 wq = *(const float4*)&sWt[(4 * k4 + kk) * O + OJ * to + 4 * j4];
        wv[4 * j4 + 0] = wq.x; wv[4 * j4 + 1] = wq.y;
        wv[4 * j4 + 2] = wq.z; wv[4 * j4 + 3] = wq.w;
      }
#pragma unroll
      for (int i = 0; i < 4; ++i) {
        float xv = xs[i][kk];
#pragma unroll
        for (int j = 0; j < OJ; ++j) acc[i][j] = fmaf(xv, wv[j], acc[i][j]);
      }
    }
  }
  // bias
#pragma unroll
  for (int j = 0; j < OJ; ++j) {
    float bb = bias[OJ * to + j];
#pragma unroll
    for (int i = 0; i < 4; ++i) acc[i][j] += bb;
  }
  // stats partials: sum / sumsq over the 64 rows of this block
  float ps[OJ], ss[OJ];
#pragma unroll
  for (int j = 0; j < OJ; ++j) {
    ps[j] = ((acc[0][j] + acc[1][j]) + (acc[2][j] + acc[3][j]));
    ss[j] = ((acc[0][j] * acc[0][j] + acc[1][j] * acc[1][j]) +
             (acc[2][j] * acc[2][j] + acc[3][j] * acc[3][j]));
  }
  __syncthreads();   // done reading sX; reuse as reduction scratch (32*O <= 4352)
#pragma unroll
  for (int j = 0; j < OJ; ++j) {
    int o = OJ * to + j;
    sX[tm * O + o] = ps[j];
    sX[16 * O + tm * O + o] = ss[j];
  }
  __syncthreads();
  if (t < O) {
    float s1 = 0.0f, s2 = 0.0f;
#pragma unroll
    for (int r2 = 0; r2 < 16; ++r2) { s1 += sX[r2 * O + t]; s2 += sX[16 * O + r2 * O + t]; }
    partials[(size_t)t * NBLK + blockIdx.x] = s1;
    partials[(size_t)(O + t) * NBLK + blockIdx.x] = s2;
  }
  if constexpr (WRITE_Y) {
#pragma unroll
    for (int i = 0; i < 4; ++i) {
#pragma unroll
      for (int j4 = 0; j4 < OJ / 4; ++j4) {
        *(float4*)&Yg[(size_t)(m0 + 4 * tm + i) * O + OJ * to + 4 * j4] =
            make_float4(acc[i][4 * j4 + 0], acc[i][4 * j4 + 1],
                        acc[i][4 * j4 + 2], acc[i][4 * j4 + 3]);
      }
    }
  }
  if constexpr (DO_MM) {
    // per-thread max/min over its 4 rows (all in the same k-group of 32)
    float vmx[OJ], vmn[OJ];
#pragma unroll
    for (int j = 0; j < OJ; ++j) {
      vmx[j] = fmaxf(fmaxf(acc[0][j], acc[1][j]), fmaxf(acc[2][j], acc[3][j]));
      vmn[j] = fminf(fminf(acc[0][j], acc[1][j]), fminf(acc[2][j], acc[3][j]));
    }
    __syncthreads();
#pragma unroll
    for (int j = 0; j < OJ; ++j) {
      int o = OJ * to + j;
      sX[tm * O + o] = vmx[j];
      sX[16 * O + tm * O + o] = vmn[j];
    }
    __syncthreads();
    // 256 threads = 2 groups x O(=128)
    int g = t >> 7, o = t & 127;
    float mx = sX[(g * 8) * O + o];
    float mn = sX[16 * O + (g * 8) * O + o];
#pragma unroll
    for (int r2 = 1; r2 < 8; ++r2) {
      mx = fmaxf(mx, sX[(g * 8 + r2) * O + o]);
      mn = fminf(mn, sX[16 * O + (g * 8 + r2) * O + o]);
    }
    int row = (m0 >> 5) + g;                   // (b,s) index
    mm[(size_t)row * O + o] = mx;
    mm[(size_t)8192 * O + (size_t)row * O + o] = mn;
  }
}

// ---------------------------------------------------------------------------
// BN finalize: reduce 4096 partials per channel -> (a, d) with a=g*rsigma,
// d = bt - mu*a. ad layout: a at [0..O), d at [128..128+O).
// ---------------------------------------------------------------------------
__global__ __launch_bounds__(256) void bn_finalize(const float* __restrict__ partials,
                                                   const float* __restrict__ g,
                                                   const float* __restrict__ bt,
                                                   float* __restrict__ ad, int O) {
  int o = blockIdx.x, t = threadIdx.x;
  const float* p1 = partials + (size_t)o * NBLK;
  const float* p2 = partials + (size_t)(O + o) * NBLK;
  float s1 = 0.0f, s2 = 0.0f;
  for (int i = t; i < NBLK; i += 256) { s1 += p1[i]; s2 += p2[i]; }
  __shared__ float r1[4], r2[4];
#pragma unroll
  for (int off = 32; off >= 1; off >>= 1) {
    s1 += __shfl_down(s1, off, 64);
    s2 += __shfl_down(s2, off, 64);
  }
  if ((t & 63) == 0) { r1[t >> 6] = s1; r2[t >> 6] = s2; }
  __syncthreads();
  if (t == 0) {
    float S1 = (r1[0] + r1[1]) + (r1[2] + r1[3]);
    float S2 = (r2[0] + r2[1]) + (r2[2] + r2[3]);
    const float invM = 1.0f / (float)MTOT;
    float mu = S1 * invM;
    float var = S2 * invM - mu * mu;
    float rs = 1.0f / sqrtf(var + 1e-5f);
    float a = g[o] * rs;
    ad[o] = a;
    ad[128 + o] = bt[o] - mu * a;
  }
}

// ---------------------------------------------------------------------------
// Final: new_points[(b,s),o] = relu(a * (a>=0 ? max : min) + d)
// ---------------------------------------------------------------------------
__global__ __launch_bounds__(256) void final_kernel(const float* __restrict__ mm,
                                                    const float* __restrict__ ad,
                                                    float* __restrict__ out) {
  int gid = blockIdx.x * 256 + threadIdx.x;   // 8192*128 exactly
  int o = gid & 127;
  float a = ad[o], d = ad[128 + o];
  float y = (a >= 0.0f) ? mm[gid] : mm[8192 * 128 + gid];
  out[gid] = fmaxf(fmaf(a, y, d), 0.0f);
}

extern "C" void kernel_launch(void* const* d_in, const int* in_sizes, int n_in,
                              void* d_out, int out_size, void* d_ws, size_t ws_size,
                              hipStream_t stream) {
  (void)in_sizes; (void)n_in; (void)out_size; (void)ws_size;
  const float* xyz    = (const float*)d_in[0];
  const float* points = (const float*)d_in[1];
  const float* w0  = (const float*)d_in[2];
  const float* b0  = (const float*)d_in[3];
  const float* g0  = (const float*)d_in[4];
  const float* bt0 = (const float*)d_in[5];
  const float* w1  = (const float*)d_in[6];
  const float* b1  = (const float*)d_in[7];
  const float* g1  = (const float*)d_in[8];
  const float* bt1 = (const float*)d_in[9];
  const float* w2  = (const float*)d_in[10];
  const float* b2  = (const float*)d_in[11];
  const float* g2  = (const float*)d_in[12];
  const float* bt2 = (const float*)d_in[13];

  float* out      = (float*)d_out;
  float* new_xyz  = out;                 // 8*1024*3 = 24576 floats
  float* out_pts  = out + 24576;         // 8*1024*128 floats

  float* wsf  = (float*)d_ws;
  int*   gidx = (int*)d_ws;                          // 262144 ints
  float* X0   = wsf + 262144;                        // 262144*68
  float* Y1   = X0 + (size_t)MTOT * 68;              // 262144*64
  float* Y2   = X0;                                  // reuse X0 region
  float* part = Y1 + (size_t)MTOT * 64;              // 2*128*4096
  float* ad1  = part + 2 * 128 * NBLK;               // 256
  float* ad2  = ad1 + 256;
  float* ad3  = ad2 + 256;
  float* mm   = ad3 + 256;                           // 2*8192*128

  fps_kernel<<<NB, 256, 0, stream>>>(xyz, new_xyz);
  ballq_kernel<<<(NB * NPT * 64) / 256, 256, 0, stream>>>(xyz, new_xyz, gidx);
  gather_kernel<<<(MTOT * 68) / 256, 256, 0, stream>>>(xyz, points, new_xyz, gidx, X0);

  mlp_gemm<67, 68, 64, false, true, false><<<NBLK, 256, 0, stream>>>(
      X0, w0, b0, nullptr, Y1, part, nullptr);
  bn_finalize<<<64, 256, 0, stream>>>(part, g0, bt0, ad1, 64);

  mlp_gemm<64, 64, 64, true, true, false><<<NBLK, 256, 0, stream>>>(
      Y1, w1, b1, ad1, Y2, part, nullptr);
  bn_finalize<<<64, 256, 0, stream>>>(part, g1, bt1, ad2, 64);

  mlp_gemm<64, 64, 128, true, false, true><<<NBLK, 256, 0, stream>>>(
      Y2, w2, b2, ad2, nullptr, part, mm);
  bn_finalize<<<128, 256, 0, stream>>>(part, g2, bt2, ad3, 128);

  final_kernel<<<(8192 * 128) / 256, 256, 0, stream>>>(mm, ad3, out_pts);
}

// Round 2
// 989.254 us; speedup vs baseline: 1.1285x; 1.1285x over previous
//
#include <hip/hip_runtime.h>
#include <cmath>

// Problem constants
#define NB 8
#define NPTS 4096
#define NPT 1024
#define NSAMP 32
#define MTOT (NB*NPT*NSAMP)   // 262144 rows for the MLP
#define NBLK 4096             // MTOT/64 GEMM blocks

typedef float v2f __attribute__((ext_vector_type(2)));

// ---------------------------------------------------------------------------
// Stage 1: farthest point sampling. One block per batch. Bitwise-exact f32
// replication of the reference (packed v_pk mul/add with contraction OFF keeps
// the separate-rounding mul-then-add order; (dx2+dy2)+dz2 sum order; argmax
// with first-index tie-break via u64 key). DPP-based wave reduction replaces
// the ds_bpermute shuffle butterfly (~500 cyc -> ~70 cyc dependent latency).
// ---------------------------------------------------------------------------
#define DPP_STAGE(CTRL) do {                                                   \
    unsigned int olo = (unsigned int)__builtin_amdgcn_update_dpp(              \
        0, (int)lo, (CTRL), 0xf, 0xf, false);                                  \
    unsigned int ohi = (unsigned int)__builtin_amdgcn_update_dpp(              \
        0, (int)hi, (CTRL), 0xf, 0xf, false);                                  \
    unsigned long long other = ((unsigned long long)ohi << 32) | olo;          \
    if (other > key) key = other;                                              \
    lo = (unsigned int)key; hi = (unsigned int)(key >> 32);                    \
  } while (0)

__global__ __launch_bounds__(256) void fps_kernel(const float* __restrict__ xyz,
                                                  float* __restrict__ new_xyz) {
#pragma clang fp contract(off)
  const int b = blockIdx.x;
  const int t = threadIdx.x;
  __shared__ float4 sxyz[NPTS];                 // 64 KiB
  __shared__ unsigned long long red[2][4];
  const float* X = xyz + (size_t)b * NPTS * 3;
  v2f px[8], py[8], pz[8], dist[8];
#pragma unroll
  for (int i = 0; i < 8; ++i) {
    int p0 = (2 * i) * 256 + t;
    int p1 = (2 * i + 1) * 256 + t;
    float x0 = X[p0 * 3 + 0], y0 = X[p0 * 3 + 1], z0 = X[p0 * 3 + 2];
    float x1 = X[p1 * 3 + 0], y1 = X[p1 * 3 + 1], z1 = X[p1 * 3 + 2];
    px[i] = (v2f){x0, x1}; py[i] = (v2f){y0, y1}; pz[i] = (v2f){z0, z1};
    sxyz[p0] = make_float4(x0, y0, z0, 0.0f);
    sxyz[p1] = make_float4(x1, y1, z1, 0.0f);
    dist[i] = (v2f){1e10f, 1e10f};
  }
  __syncthreads();
  int far = 0;
  float* outp = new_xyz + (size_t)b * NPT * 3;
  for (int s = 0; s < NPT; ++s) {
    float4 c = sxyz[far];
    if (t == 0) { outp[s * 3 + 0] = c.x; outp[s * 3 + 1] = c.y; outp[s * 3 + 2] = c.z; }
    v2f cx = (v2f){c.x, c.x}, cy = (v2f){c.y, c.y}, cz = (v2f){c.z, c.z};
    float bestv = -1.0f; int besti = 0;
#pragma unroll
    for (int i = 0; i < 8; ++i) {
      v2f dx = px[i] - cx;                      // v_pk_add (neg) — exact sub
      v2f dy = py[i] - cy;
      v2f dz = pz[i] - cz;
      v2f d = (dx * dx + dy * dy) + dz * dz;    // contract(off): pk mul/add, ref order
      v2f nd = __builtin_elementwise_min(dist[i], d);
      dist[i] = nd;
      // ascending point index order -> strict > keeps lowest index on tie
      if (nd.x > bestv) { bestv = nd.x; besti = (2 * i) * 256 + t; }
      if (nd.y > bestv) { bestv = nd.y; besti = (2 * i + 1) * 256 + t; }
    }
    // pack: higher value wins; equal value -> smaller index wins
    unsigned long long key = ((unsigned long long)__float_as_uint(bestv) << 32)
                           | (unsigned int)(~besti);
    unsigned int lo = (unsigned int)key, hi = (unsigned int)(key >> 32);
    // wave64 max-reduce via DPP; identity 0 is safe (keys >= 0); result in lane 63
    DPP_STAGE(0x111);   // row_shr:1
    DPP_STAGE(0x112);   // row_shr:2
    DPP_STAGE(0x114);   // row_shr:4
    DPP_STAGE(0x118);   // row_shr:8
    DPP_STAGE(0x142);   // row_bcast:15
    DPP_STAGE(0x143);   // row_bcast:31
    if ((t & 63) == 63) red[s & 1][t >> 6] = key;
    __syncthreads();
    unsigned long long k0 = red[s & 1][0], k1 = red[s & 1][1];
    unsigned long long k2 = red[s & 1][2], k3 = red[s & 1][3];
    if (k1 > k0) k0 = k1;
    if (k3 > k2) k2 = k3;
    if (k2 > k0) k0 = k2;
    far = (int)(~(unsigned int)k0);
  }
}

// ---------------------------------------------------------------------------
// Stage 2: ball query. One wave per (b,s). First 32 indices in ascending order
// with dist <= r^2; pad with first match.
// ---------------------------------------------------------------------------
__global__ __launch_bounds__(256) void ballq_kernel(const float* __restrict__ xyz,
                                                    const float* __restrict__ new_xyz,
                                                    int* __restrict__ gidx) {
  int w = (blockIdx.x * 256 + threadIdx.x) >> 6;   // 8192 waves
  int lane = threadIdx.x & 63;
  int b = w >> 10;
  const float* X = xyz + (size_t)b * NPTS * 3;
  float cx = new_xyz[w * 3 + 0], cy = new_xyz[w * 3 + 1], cz = new_xyz[w * 3 + 2];
  int* out = gidx + (size_t)w * NSAMP;
  int cnt = 0, first = -1;
  for (int c = 0; c < NPTS / 64; ++c) {
    int p = c * 64 + lane;
    float dx = __fsub_rn(X[p * 3 + 0], cx);
    float dy = __fsub_rn(X[p * 3 + 1], cy);
    float dz = __fsub_rn(X[p * 3 + 2], cz);
    float d = __fadd_rn(__fadd_rn(__fmul_rn(dx, dx), __fmul_rn(dy, dy)), __fmul_rn(dz, dz));
    bool inr = !(d > 0.04f);   // f32(0.2**2) == 0.04f
    unsigned long long mask = __ballot(inr);
    if (mask) {
      if (first < 0) first = c * 64 + (int)__builtin_ctzll(mask);
      if (inr) {
        int pos = cnt + (int)__builtin_popcountll(mask & ((1ull << lane) - 1ull));
        if (pos < NSAMP) out[pos] = p;
      }
      cnt += (int)__builtin_popcountll(mask);
      if (cnt >= NSAMP) break;
    }
  }
  if (lane >= cnt && lane < NSAMP) out[lane] = first;
}

// ---------------------------------------------------------------------------
// Stage 3: gather + concat -> X0 (MTOT x 68, col67 zero pad)
// ---------------------------------------------------------------------------
__global__ __launch_bounds__(256) void gather_kernel(const float* __restrict__ xyz,
                                                     const float* __restrict__ points,
                                                     const float* __restrict__ new_xyz,
                                                     const int* __restrict__ gidx,
                                                     float* __restrict__ X0) {
  int gid = blockIdx.x * 256 + threadIdx.x;       // < MTOT*68 exactly
  int m = gid / 68;
  int c = gid - m * 68;
  int idx = gidx[m];
  int b = m >> 15;                                 // 32768 rows per batch
  float v;
  if (c < 3) {
    v = __fsub_rn(xyz[((size_t)b * NPTS + idx) * 3 + c],
                  new_xyz[(size_t)(m >> 5) * 3 + c]);
  } else if (c < 67) {
    v = points[((size_t)b * NPTS + idx) * 64 + (c - 3)];
  } else {
    v = 0.0f;
  }
  X0[gid] = v;
}

// ---------------------------------------------------------------------------
// Stage 4: MLP layer GEMM. 64xO tile per block, 256 threads.
// Thread (to=t&15, tm=t>>4) computes rows 4*tm..+3, cols OJ*to..+OJ-1.
// Optionally applies previous layer's BN+ReLU (a,d) while staging input.
// Writes per-block per-channel sum / sumsq partials (deterministic stats).
// DO_MM: instead of writing Y, max/min-pool pre-activations over k (32 rows).
// ---------------------------------------------------------------------------
template<int KDIM, int XSTRIDE, int O, bool NORM_IN, bool WRITE_Y, bool DO_MM>
__global__ __launch_bounds__(256) void mlp_gemm(const float* __restrict__ Xg,
                                                const float* __restrict__ Wg,
                                                const float* __restrict__ bias,
                                                const float* __restrict__ ad,
                                                float* __restrict__ Yg,
                                                float* __restrict__ partials,
                                                float* __restrict__ mm) {
  constexpr int KP = (KDIM + 3) & ~3;   // 68 or 64
  constexpr int KP4 = KP / 4;
  constexpr int OJ = O / 16;            // 4 or 8
  __shared__ __align__(16) float sX[64 * 68];
  __shared__ __align__(16) float sWt[KP * O];
  const int t = threadIdx.x;
  const int m0 = blockIdx.x * 64;

  // stage W transposed: sWt[k*O+o] = W[o*KDIM+k]; consecutive t -> consecutive o
  for (int i = t; i < O * KDIM; i += 256) {
    int k = i / O;            // O is power of 2
    int o = i - k * O;
    sWt[k * O + o] = Wg[o * KDIM + k];
  }
  if (KP > KDIM) {
    if (t < O) {
      for (int k = KDIM; k < KP; ++k) sWt[k * O + t] = 0.0f;
    }
  }
  // stage X tile (apply BN+ReLU of previous layer if NORM_IN)
  {
    int r = t >> 2, q = t & 3;
    const float* src = Xg + (size_t)(m0 + r) * XSTRIDE;
    for (int c4 = q; c4 < KP4; c4 += 4) {
      float4 v = *(const float4*)(src + 4 * c4);
      if constexpr (NORM_IN) {
        float4 a = *(const float4*)(ad + 4 * c4);
        float4 d = *(const float4*)(ad + 128 + 4 * c4);
        v.x = fmaxf(fmaf(a.x, v.x, d.x), 0.0f);
        v.y = fmaxf(fmaf(a.y, v.y, d.y), 0.0f);
        v.z = fmaxf(fmaf(a.z, v.z, d.z), 0.0f);
        v.w = fmaxf(fmaf(a.w, v.w, d.w), 0.0f);
      }
      *(float4*)&sX[r * 68 + 4 * c4] = v;
    }
  }
  __syncthreads();

  const int to = t & 15, tm = t >> 4;
  float acc[4][OJ];
#pragma unroll
  for (int i = 0; i < 4; ++i)
#pragma unroll
    for (int j = 0; j < OJ; ++j) acc[i][j] = 0.0f;

#pragma unroll
  for (int k4 = 0; k4 < KP4; ++k4) {
    float xs[4][4];
#pragma unroll
    for (int i = 0; i < 4; ++i) {
      float4 v = *(const float4*)&sX[(4 * tm + i) * 68 + 4 * k4];
      xs[i][0] = v.x; xs[i][1] = v.y; xs[i][2] = v.z; xs[i][3] = v.w;
    }
#pragma unroll
    for (int kk = 0; kk < 4; ++kk) {
      float wv[OJ];
#pragma unroll
      for (int j4 = 0; j4 < OJ / 4; ++j4) {
        float4 wq = *(const float4*)&sWt[(4 * k4 + kk) * O + OJ * to + 4 * j4];
        wv[4 * j4 + 0] = wq.x; wv[4 * j4 + 1] = wq.y;
        wv[4 * j4 + 2] = wq.z; wv[4 * j4 + 3] = wq.w;
      }
#pragma unroll
      for (int i = 0; i < 4; ++i) {
        float xv = xs[i][kk];
#pragma unroll
        for (int j = 0; j < OJ; ++j) acc[i][j] = fmaf(xv, wv[j], acc[i][j]);
      }
    }
  }
  // bias
#pragma unroll
  for (int j = 0; j < OJ; ++j) {
    float bb = bias[OJ * to + j];
#pragma unroll
    for (int i = 0; i < 4; ++i) acc[i][j] += bb;
  }
  // stats partials: sum / sumsq over the 64 rows of this block
  float ps[OJ], ss[OJ];
#pragma unroll
  for (int j = 0; j < OJ; ++j) {
    ps[j] = ((acc[0][j] + acc[1][j]) + (acc[2][j] + acc[3][j]));
    ss[j] = ((acc[0][j] * acc[0][j] + acc[1][j] * acc[1][j]) +
             (acc[2][j] * acc[2][j] + acc[3][j] * acc[3][j]));
  }
  __syncthreads();   // done reading sX; reuse as reduction scratch (32*O <= 4352)
#pragma unroll
  for (int j = 0; j < OJ; ++j) {
    int o = OJ * to + j;
    sX[tm * O + o] = ps[j];
    sX[16 * O + tm * O + o] = ss[j];
  }
  __syncthreads();
  if (t < O) {
    float s1 = 0.0f, s2 = 0.0f;
#pragma unroll
    for (int r2 = 0; r2 < 16; ++r2) { s1 += sX[r2 * O + t]; s2 += sX[16 * O + r2 * O + t]; }
    partials[(size_t)t * NBLK + blockIdx.x] = s1;
    partials[(size_t)(O + t) * NBLK + blockIdx.x] = s2;
  }
  if constexpr (WRITE_Y) {
#pragma unroll
    for (int i = 0; i < 4; ++i) {
#pragma unroll
      for (int j4 = 0; j4 < OJ / 4; ++j4) {
        *(float4*)&Yg[(size_t)(m0 + 4 * tm + i) * O + OJ * to + 4 * j4] =
            make_float4(acc[i][4 * j4 + 0], acc[i][4 * j4 + 1],
                        acc[i][4 * j4 + 2], acc[i][4 * j4 + 3]);
      }
    }
  }
  if constexpr (DO_MM) {
    // per-thread max/min over its 4 rows (all in the same k-group of 32)
    float vmx[OJ], vmn[OJ];
#pragma unroll
    for (int j = 0; j < OJ; ++j) {
      vmx[j] = fmaxf(fmaxf(acc[0][j], acc[1][j]), fmaxf(acc[2][j], acc[3][j]));
      vmn[j] = fminf(fminf(acc[0][j], acc[1][j]), fminf(acc[2][j], acc[3][j]));
    }
    __syncthreads();
#pragma unroll
    for (int j = 0; j < OJ; ++j) {
      int o = OJ * to + j;
      sX[tm * O + o] = vmx[j];
      sX[16 * O + tm * O + o] = vmn[j];
    }
    __syncthreads();
    // 256 threads = 2 groups x O(=128)
    int g = t >> 7, o = t & 127;
    float mx = sX[(g * 8) * O + o];
    float mn = sX[16 * O + (g * 8) * O + o];
#pragma unroll
    for (int r2 = 1; r2 < 8; ++r2) {
      mx = fmaxf(mx, sX[(g * 8 + r2) * O + o]);
      mn = fminf(mn, sX[16 * O + (g * 8 + r2) * O + o]);
    }
    int row = (m0 >> 5) + g;                   // (b,s) index
    mm[(size_t)row * O + o] = mx;
    mm[(size_t)8192 * O + (size_t)row * O + o] = mn;
  }
}

// ---------------------------------------------------------------------------
// BN finalize: reduce 4096 partials per channel -> (a, d) with a=g*rsigma,
// d = bt - mu*a. ad layout: a at [0..O), d at [128..128+O).
// ---------------------------------------------------------------------------
__global__ __launch_bounds__(256) void bn_finalize(const float* __restrict__ partials,
                                                   const float* __restrict__ g,
                                                   const float* __restrict__ bt,
                                                   float* __restrict__ ad, int O) {
  int o = blockIdx.x, t = threadIdx.x;
  const float* p1 = partials + (size_t)o * NBLK;
  const float* p2 = partials + (size_t)(O + o) * NBLK;
  float s1 = 0.0f, s2 = 0.0f;
  for (int i = t; i < NBLK; i += 256) { s1 += p1[i]; s2 += p2[i]; }
  __shared__ float r1[4], r2[4];
#pragma unroll
  for (int off = 32; off >= 1; off >>= 1) {
    s1 += __shfl_down(s1, off, 64);
    s2 += __shfl_down(s2, off, 64);
  }
  if ((t & 63) == 0) { r1[t >> 6] = s1; r2[t >> 6] = s2; }
  __syncthreads();
  if (t == 0) {
    float S1 = (r1[0] + r1[1]) + (r1[2] + r1[3]);
    float S2 = (r2[0] + r2[1]) + (r2[2] + r2[3]);
    const float invM = 1.0f / (float)MTOT;
    float mu = S1 * invM;
    float var = S2 * invM - mu * mu;
    float rs = 1.0f / sqrtf(var + 1e-5f);
    float a = g[o] * rs;
    ad[o] = a;
    ad[128 + o] = bt[o] - mu * a;
  }
}

// ---------------------------------------------------------------------------
// Final: new_points[(b,s),o] = relu(a * (a>=0 ? max : min) + d)
// ---------------------------------------------------------------------------
__global__ __launch_bounds__(256) void final_kernel(const float* __restrict__ mm,
                                                    const float* __restrict__ ad,
                                                    float* __restrict__ out) {
  int gid = blockIdx.x * 256 + threadIdx.x;   // 8192*128 exactly
  int o = gid & 127;
  float a = ad[o], d = ad[128 + o];
  float y = (a >= 0.0f) ? mm[gid] : mm[8192 * 128 + gid];
  out[gid] = fmaxf(fmaf(a, y, d), 0.0f);
}

extern "C" void kernel_launch(void* const* d_in, const int* in_sizes, int n_in,
                              void* d_out, int out_size, void* d_ws, size_t ws_size,
                              hipStream_t stream) {
  (void)in_sizes; (void)n_in; (void)out_size; (void)ws_size;
  const float* xyz    = (const float*)d_in[0];
  const float* points = (const float*)d_in[1];
  const float* w0  = (const float*)d_in[2];
  const float* b0  = (const float*)d_in[3];
  const float* g0  = (const float*)d_in[4];
  const float* bt0 = (const float*)d_in[5];
  const float* w1  = (const float*)d_in[6];
  const float* b1  = (const float*)d_in[7];
  const float* g1  = (const float*)d_in[8];
  const float* bt1 = (const float*)d_in[9];
  const float* w2  = (const float*)d_in[10];
  const float* b2  = (const float*)d_in[11];
  const float* g2  = (const float*)d_in[12];
  const float* bt2 = (const float*)d_in[13];

  float* out      = (float*)d_out;
  float* new_xyz  = out;                 // 8*1024*3 = 24576 floats
  float* out_pts  = out + 24576;         // 8*1024*128 floats

  float* wsf  = (float*)d_ws;
  int*   gidx = (int*)d_ws;                          // 262144 ints
  float* X0   = wsf + 262144;                        // 262144*68
  float* Y1   = X0 + (size_t)MTOT * 68;              // 262144*64
  float* Y2   = X0;                                  // reuse X0 region
  float* part = Y1 + (size_t)MTOT * 64;              // 2*128*4096
  float* ad1  = part + 2 * 128 * NBLK;               // 256
  float* ad2  = ad1 + 256;
  float* ad3  = ad2 + 256;
  float* mm   = ad3 + 256;                           // 2*8192*128

  fps_kernel<<<NB, 256, 0, stream>>>(xyz, new_xyz);
  ballq_kernel<<<(NB * NPT * 64) / 256, 256, 0, stream>>>(xyz, new_xyz, gidx);
  gather_kernel<<<(MTOT * 68) / 256, 256, 0, stream>>>(xyz, points, new_xyz, gidx, X0);

  mlp_gemm<67, 68, 64, false, true, false><<<NBLK, 256, 0, stream>>>(
      X0, w0, b0, nullptr, Y1, part, nullptr);
  bn_finalize<<<64, 256, 0, stream>>>(part, g0, bt0, ad1, 64);

  mlp_gemm<64, 64, 64, true, true, false><<<NBLK, 256, 0, stream>>>(
      Y1, w1, b1, ad1, Y2, part, nullptr);
  bn_finalize<<<64, 256, 0, stream>>>(part, g1, bt1, ad2, 64);

  mlp_gemm<64, 64, 128, true, false, true><<<NBLK, 256, 0, stream>>>(
      Y2, w2, b2, ad2, nullptr, part, mm);
  bn_finalize<<<128, 256, 0, stream>>>(part, g2, bt2, ad3, 128);

  final_kernel<<<(8192 * 128) / 256, 256, 0, stream>>>(mm, ad3, out_pts);
}